// Round 4
// baseline (433.497 us; speedup 1.0000x reference)
//
#include <hip/hip_runtime.h>

// GetCostVolume: out[0, 0:C,  d,h,w] = x[c,h,w]   (broadcast over d)
//                out[0, C:2C, d,h,w] = bilinear_zeros(y[c], ix(d,h,w), iy(h))
// B=1, C=32, H=128, W=256, D=48.
//
// v4 (resubmit after infra failure): sequential store streams. v1-v3
// established the kernel is pinned at ~2.5 TB/s write BW independent of chunk
// size (256B/1KB) and cache policy (nt/plain), while the harness fill hits
// 6.3 TB/s on the same buffer. The remaining difference is the macro walk:
// v1-v3 write 1-KB bursts at power-of-2 strides (128 KB / 6 MB) across 3072
// planes (DRAM bank aliasing / page thrash); the fill walks sequentially.
// v4: block = (c, 8d, 32h), each wave streams 32 KB sequential per (c,d)
// plane segment. Gather switches to per-lane scalar ds_read2_b32 pairs from
// a single-channel LDS row tile.

typedef float v4f __attribute__((ext_vector_type(4)));

namespace {
constexpr int C = 32, D = 48, H = 128, W = 256;
constexpr int HW  = H * W;        // 32768
constexpr int DHW = D * HW;       // 1,572,864
constexpr int SPAN = 324;         // staged x window: x = XLO + j, j in [0,324)
constexpr int XLO  = -66;
constexpr int ROWS = 34;          // y rows staged per 32-h chunk
constexpr int SP   = SPAN + 1;    // 325 (odd -> row-to-row bank shift)
}

__global__ __launch_bounds__(512, 4) void cost_volume_kernel(
    const float* __restrict__ x, const float* __restrict__ y,
    const float* __restrict__ disp, float* __restrict__ out)
{
    __shared__ float ys[ROWS * SP];        // 34*325*4 = 44,200 B -> 3 blocks/CU

    const int t     = threadIdx.x;
    const int c     = blockIdx.x;          // 32 channels
    const int dbase = blockIdx.y * 8;      // 6 d-groups of 8
    const int h0    = blockIdx.z * 32;     // 4 h-chunks
    const int wave  = t >> 6;              // 8 waves: wave = d within group
    const int lane  = t & 63;
    const int w0    = 4 * lane;            // lane covers w-quad -> full W per wave

    // ---- left-half x rows: issue loads early (4 rows per wave) ----
    v4f xv[4];
#pragma unroll
    for (int q = 0; q < 4; ++q)
        xv[q] = *(const v4f*)(x + c * HW + (h0 + wave * 4 + q) * W + w0);

    // ---- row window for this h-chunk (block-uniform) ----
    const float gy0 = (float)h0 / 63.5f - 1.0f;
    const float iy0 = ((gy0 + 1.0f) * 128.0f - 1.0f) * 0.5f;
    const int   rlo = (int)floorf(iy0);    // rows rlo .. rlo+33 cover all h in chunk

    // ---- stage y[c] rows [rlo, rlo+34) x span [-66, 258), zeros OOB ----
    const float* ysrc = y + c * HW;
    for (int i = t; i < ROWS * SPAN; i += 512) {
        const int r  = i / SPAN;           // magic-mul division
        const int j  = i - r * SPAN;
        const int yr = rlo + r;
        const int xg = XLO + j;
        float v = 0.0f;
        if (yr >= 0 && yr < H && xg >= 0 && xg < W) v = ysrc[yr * W + xg];
        ys[r * SP + j] = v;
    }
    __syncthreads();

    // ---- warped half: wave owns d, streams 32 sequential 1-KB rows ----
    const int d = dbase + wave;
    const float* dp   = disp + d * HW + h0 * W + w0;
    float*       wout = out + (C + c) * DHW + d * HW + h0 * W + w0;

    for (int hh = 0; hh < 32; ++hh) {
        const int h = h0 + hh;
        const v4f dv = *(const v4f*)(dp + hh * W);

        // per-h (lane-uniform) y interpolation params
        const float gyh = (float)h / 63.5f - 1.0f;
        const float iyh = ((gyh + 1.0f) * 128.0f - 1.0f) * 0.5f;
        const float y0f = floorf(iyh);
        const float wy  = iyh - y0f;
        const float omy = 1.0f - wy;
        const int   r0  = (int)y0f - rlo;              // 0..32
        const float* row0 = ys + r0 * SP;
        const float* row1 = row0 + SP;

        float res[4];
#pragma unroll
        for (int k = 0; k < 4; ++k) {
            const float cur = (float)(w0 + k) - dv[k];
            const float gx  = cur / 127.5f - 1.0f;                // (W-1)/2
            const float ix  = ((gx + 1.0f) * 256.0f - 1.0f) * 0.5f;
            const float x0f = floorf(ix);
            const float wx  = ix - x0f;
            const int j = min(max((int)x0f - XLO, 0), SPAN - 2);  // safety clamp
            const float omx = 1.0f - wx;
            const float w00 = omx * omy, w01 = wx * omy;
            const float w10 = omx * wy,  w11 = wx * wy;
            const float v00 = row0[j], v01 = row0[j + 1];         // ds_read2_b32
            const float v10 = row1[j], v11 = row1[j + 1];
            res[k] = fmaf(v11, w11, fmaf(v10, w10,
                      fmaf(v01, w01, v00 * w00)));
        }
        const v4f r = { res[0], res[1], res[2], res[3] };
        *(v4f*)(wout + hh * W) = r;
    }

    // ---- left half: broadcast x rows over this block's 8 d ----
#pragma unroll
    for (int dd = 0; dd < 8; ++dd) {
        float* lp = out + c * DHW + (dbase + dd) * HW + (h0 + wave * 4) * W + w0;
#pragma unroll
        for (int q = 0; q < 4; ++q)
            *(v4f*)(lp + q * W) = xv[q];
    }
}

extern "C" void kernel_launch(void* const* d_in, const int* in_sizes, int n_in,
                              void* d_out, int out_size, void* d_ws, size_t ws_size,
                              hipStream_t stream) {
    const float* x    = (const float*)d_in[0];
    const float* y    = (const float*)d_in[1];
    const float* disp = (const float*)d_in[2];
    float* out = (float*)d_out;

    // (c=32) x (d-groups=6) x (h-chunks=4) = 768 blocks, 512 threads,
    // 44.2 KB LDS -> 3 blocks/CU = 24 waves/CU, grid = exactly 3 per CU.
    cost_volume_kernel<<<dim3(32, 6, 4), dim3(512), 0, stream>>>(x, y, disp, out);
}